// Round 1
// baseline (230.425 us; speedup 1.0000x reference)
//
#include <hip/hip_runtime.h>

// Haar DWT, mode=0 (no pad).
// in : (2,16,16,256,256) f32  -> plane pl = b*256 + pcd in [0,512), each plane 256x256
// out: (2,64,16,128,128) f32  -> flat (b*1024 + s*256 + pcd)*16384 + h2*128 + w2
//
// Per 2x2 quad (a=ev/ev, b=od/ev, c=ev/od, d=od/od), all *0.5:
//   LL = a+b+c+d ; HL = -a-b+c+d ; LH = -a+b-c+d ; HH = a-b-c+d
//
// v2: each thread processes TWO units — the same (pcd,h2,w4) for batch 0 and batch 1.
//   batch-1 addresses are batch-0 + 16,777,216 floats on BOTH input and output
//   (in: +256 planes * 65536; out: +1024*16384), so the second unit costs zero
//   address math, doubles in-flight loads per wave (4 -> 8 x 16B), and halves
//   the grid (8192 -> 4096 blocks). Data regs: 8 x v4f = 32 VGPR -> still 8 waves/SIMD.
//
//   loads : 8x 16B nontemporal, all independent, issued back-to-back
//   stores: 8x 16B nontemporal, fully coalesced (512B/half-wave per subband row)

typedef float v4f __attribute__((ext_vector_type(4)));

__device__ __forceinline__ void haar4(const v4f r0a, const v4f r0b,
                                      const v4f r1a, const v4f r1b,
                                      v4f& LL, v4f& HL, v4f& LH, v4f& HH) {
    // r0a = a0 c0 a1 c1 ; r0b = a2 c2 a3 c3 (row 2h)
    // r1a = b0 d0 b1 d1 ; r1b = b2 d2 b3 d3 (row 2h+1)
    const v4f s0 = r0a + r1a;   // se0 so0 se1 so1
    const v4f s1 = r0b + r1b;   // se2 so2 se3 so3
    const v4f d0 = r0a - r1a;   // de0 do0 de1 do1
    const v4f d1 = r0b - r1b;   // de2 do2 de3 do3
    LL = v4f{  0.5f * (s0.x + s0.y),  0.5f * (s0.z + s0.w),  0.5f * (s1.x + s1.y),  0.5f * (s1.z + s1.w) };
    HL = v4f{  0.5f * (s0.y - s0.x),  0.5f * (s0.w - s0.z),  0.5f * (s1.y - s1.x),  0.5f * (s1.w - s1.z) };
    LH = v4f{ -0.5f * (d0.x + d0.y), -0.5f * (d0.z + d0.w), -0.5f * (d1.x + d1.y), -0.5f * (d1.z + d1.w) };
    HH = v4f{  0.5f * (d0.x - d0.y),  0.5f * (d0.z - d0.w),  0.5f * (d1.x - d1.y),  0.5f * (d1.z - d1.w) };
}

__global__ __launch_bounds__(256) void dwt_haar_fwd(const float* __restrict__ in,
                                                    float* __restrict__ out) {
    const int idx = blockIdx.x * 256 + threadIdx.x;   // 0 .. 1,048,576 (batch-0 units)
    const int w4  = idx & 31;           // group of 4 output cols (32 per 128-wide row)
    const int t   = idx >> 5;
    const int h2  = t & 127;            // output row
    const int pcd = t >> 7;             // c*16+d, 0..255 (batch 0 plane)

    const float* rbase = in + pcd * 65536 + (h2 << 1) * 256 + (w4 << 3);
    const v4f* pA0 = (const v4f*)(rbase);                   // b0, row 2h2
    const v4f* pA1 = (const v4f*)(rbase + 256);             // b0, row 2h2+1
    const v4f* pB0 = (const v4f*)(rbase + 16777216);        // b1, row 2h2
    const v4f* pB1 = (const v4f*)(rbase + 16777216 + 256);  // b1, row 2h2+1

    // issue all 8 independent loads before any use
    const v4f A0a = __builtin_nontemporal_load(pA0);
    const v4f A0b = __builtin_nontemporal_load(pA0 + 1);
    const v4f A1a = __builtin_nontemporal_load(pA1);
    const v4f A1b = __builtin_nontemporal_load(pA1 + 1);
    const v4f B0a = __builtin_nontemporal_load(pB0);
    const v4f B0b = __builtin_nontemporal_load(pB0 + 1);
    const v4f B1a = __builtin_nontemporal_load(pB1);
    const v4f B1b = __builtin_nontemporal_load(pB1 + 1);

    float* obase = out + (size_t)pcd * 16384 + (h2 << 7) + (w4 << 2);

    v4f LL, HL, LH, HH;
    haar4(A0a, A0b, A1a, A1b, LL, HL, LH, HH);
    __builtin_nontemporal_store(LL, (v4f*)(obase           ));  // b0 s=0
    __builtin_nontemporal_store(HL, (v4f*)(obase + 4194304 ));  // b0 s=1: +256*16384
    __builtin_nontemporal_store(LH, (v4f*)(obase + 8388608 ));  // b0 s=2
    __builtin_nontemporal_store(HH, (v4f*)(obase + 12582912));  // b0 s=3

    haar4(B0a, B0b, B1a, B1b, LL, HL, LH, HH);
    float* obase2 = obase + 16777216;                           // b=1: +1024*16384
    __builtin_nontemporal_store(LL, (v4f*)(obase2           ));
    __builtin_nontemporal_store(HL, (v4f*)(obase2 + 4194304 ));
    __builtin_nontemporal_store(LH, (v4f*)(obase2 + 8388608 ));
    __builtin_nontemporal_store(HH, (v4f*)(obase2 + 12582912));
}

extern "C" void kernel_launch(void* const* d_in, const int* in_sizes, int n_in,
                              void* d_out, int out_size, void* d_ws, size_t ws_size,
                              hipStream_t stream) {
    const float* x = (const float*)d_in[0];
    float* out = (float*)d_out;
    // total threads = 256 planes * 128 rows * 32 col-quads = 1,048,576 (2 units each)
    dwt_haar_fwd<<<4096, 256, 0, stream>>>(x, out);
}

// Round 2
// 222.328 us; speedup vs baseline: 1.0364x; 1.0364x over previous
//
#include <hip/hip_runtime.h>

// Haar DWT, mode=0 (no pad).
// in : (2,16,16,256,256) f32  -> plane pl = b*256 + pcd in [0,512), each plane 256x256
// out: (2,64,16,128,128) f32  -> flat (b*1024 + s*256 + pcd)*16384 + h2*128 + w2
//
// Per 2x2 quad (a=ev/ev, b=od/ev, c=ev/od, d=od/od), all *0.5:
//   LL = a+b+c+d ; HL = -a-b+c+d ; LH = -a+b-c+d ; HH = a-b-c+d
//
// Thread layout: idx = (plane[9b], h2[7b], w4[5b]); w4 indexes groups of 4 output cols.
//   loads : 2x 16B per input row (rows 2h2, 2h2+1) -> contiguous 32 B/thread/row;
//           per load instruction each 32-lane half-wave covers 1 KiB contiguous (8 full lines)
//   stores: 1x 16B per subband -> 512 B contiguous per 32-lane half-wave, fully coalesced
// Nontemporal on both sides: pure streaming, zero reuse -> don't churn L2.
//
// v2 post-mortem (230 µs, reverted): 2 units/thread at +64 MiB offsets doubled the
// far-apart write-stream count per wave and added unfoldable 64-bit address math;
// per-thread MLP was never the limiter. This v1 structure measured 222-223 µs across
// two independent sessions.

typedef float v4f __attribute__((ext_vector_type(4)));  // native vector: OK for nontemporal builtins

__global__ __launch_bounds__(256) void dwt_haar_fwd(const float* __restrict__ in,
                                                    float* __restrict__ out) {
    const int idx = blockIdx.x * 256 + threadIdx.x;   // 0 .. 2,097,152
    const int w4  = idx & 31;           // group of 4 output cols (32 per 128-wide row)
    const int t   = idx >> 5;
    const int h2  = t & 127;            // output row
    const int pl  = t >> 7;             // input plane 0..511
    const int b   = pl >> 8;            // batch
    const int pcd = pl & 255;           // c*16+d

    const float* rbase = in + pl * 65536 + (h2 << 1) * 256 + (w4 << 3);
    const v4f* p0 = (const v4f*)rbase;           // row 2h2
    const v4f* p1 = (const v4f*)(rbase + 256);   // row 2h2+1
    const v4f r0a = __builtin_nontemporal_load(p0);     // a0 c0 a1 c1
    const v4f r0b = __builtin_nontemporal_load(p0 + 1); // a2 c2 a3 c3
    const v4f r1a = __builtin_nontemporal_load(p1);     // b0 d0 b1 d1
    const v4f r1b = __builtin_nontemporal_load(p1 + 1); // b2 d2 b3 d3

    // sums/diffs: s_e=a+b, s_o=c+d, d_e=a-b, d_o=c-d for 4 output columns
    const v4f s0 = r0a + r1a;   // se0 so0 se1 so1
    const v4f s1 = r0b + r1b;   // se2 so2 se3 so3
    const v4f d0 = r0a - r1a;   // de0 do0 de1 do1
    const v4f d1 = r0b - r1b;   // de2 do2 de3 do3

    const v4f LL = {  0.5f * (s0.x + s0.y),  0.5f * (s0.z + s0.w),  0.5f * (s1.x + s1.y),  0.5f * (s1.z + s1.w) };
    const v4f HL = {  0.5f * (s0.y - s0.x),  0.5f * (s0.w - s0.z),  0.5f * (s1.y - s1.x),  0.5f * (s1.w - s1.z) };
    const v4f LH = { -0.5f * (d0.x + d0.y), -0.5f * (d0.z + d0.w), -0.5f * (d1.x + d1.y), -0.5f * (d1.z + d1.w) };
    const v4f HH = {  0.5f * (d0.x - d0.y),  0.5f * (d0.z - d0.w),  0.5f * (d1.x - d1.y),  0.5f * (d1.z - d1.w) };

    float* obase = out + (size_t)(b * 1024 + pcd) * 16384 + (h2 << 7) + (w4 << 2);
    __builtin_nontemporal_store(LL, (v4f*)(obase           ));  // s=0
    __builtin_nontemporal_store(HL, (v4f*)(obase + 4194304 ));  // s=1: +256*16384
    __builtin_nontemporal_store(LH, (v4f*)(obase + 8388608 ));  // s=2
    __builtin_nontemporal_store(HH, (v4f*)(obase + 12582912));  // s=3
}

extern "C" void kernel_launch(void* const* d_in, const int* in_sizes, int n_in,
                              void* d_out, int out_size, void* d_ws, size_t ws_size,
                              hipStream_t stream) {
    const float* x = (const float*)d_in[0];
    float* out = (float*)d_out;
    // total threads = 512 planes * 128 rows * 32 col-quads = 2,097,152
    dwt_haar_fwd<<<8192, 256, 0, stream>>>(x, out);
}